// Round 1
// 260.175 us; speedup vs baseline: 1.0033x; 1.0033x over previous
//
#include <hip/hip_runtime.h>

typedef __bf16 bf16;
typedef __bf16 bf16x4 __attribute__((ext_vector_type(4)));
typedef __bf16 bf16x8 __attribute__((ext_vector_type(8)));
typedef float  f32x4  __attribute__((ext_vector_type(4)));
typedef float  f32x16 __attribute__((ext_vector_type(16)));
typedef unsigned int u32x2 __attribute__((ext_vector_type(2)));
typedef unsigned int u32x4 __attribute__((ext_vector_type(4)));

#define NB   2
#define NL   4096
#define ND   512
#define NH   8
#define NHD  64

// async global->LDS, 16 bytes per lane. LDS dest must be wave-uniform base + lane*16.
static __device__ __forceinline__ void g2l16(const bf16* g, bf16* l) {
    __builtin_amdgcn_global_load_lds(
        (const __attribute__((address_space(1))) unsigned int*)g,
        (__attribute__((address_space(3))) unsigned int*)l, 16, 0, 0);
}

// ---------------------------------------------------------------------------
// Kernel 0: all f32 -> bf16 conversions in one dispatch (memory-bound).
// ---------------------------------------------------------------------------
__global__ __launch_bounds__(256) void cvt_all(
    const float* __restrict__ q, const float* __restrict__ k, const float* __restrict__ v,
    const float* __restrict__ Wq, const float* __restrict__ Wk,
    const float* __restrict__ Wv, const float* __restrict__ Wo,
    bf16* __restrict__ qb, bf16* __restrict__ kb, bf16* __restrict__ vb,
    bf16* __restrict__ wqb, bf16* __restrict__ wkb,
    bf16* __restrict__ wvb, bf16* __restrict__ wob)
{
    const int z = blockIdx.z;
    const float* src; bf16* dst; int n4;
    switch (z) {
        case 0: src = q;  dst = qb;  n4 = NB * NL * ND / 4; break;
        case 1: src = k;  dst = kb;  n4 = NB * NL * ND / 4; break;
        case 2: src = v;  dst = vb;  n4 = NB * NL * ND / 4; break;
        case 3: src = Wq; dst = wqb; n4 = ND * ND / 4; break;
        case 4: src = Wk; dst = wkb; n4 = ND * ND / 4; break;
        case 5: src = Wv; dst = wvb; n4 = ND * ND / 4; break;
        default: src = Wo; dst = wob; n4 = ND * ND / 4; break;
    }
    for (int i = blockIdx.x * 256 + threadIdx.x; i < n4; i += gridDim.x * 256) {
        const f32x4 a = *(const f32x4*)(src + (size_t)i * 4);
        bf16x4 o;
        #pragma unroll
        for (int j = 0; j < 4; ++j) o[j] = (bf16)a[j];
        *(bf16x4*)(dst + (size_t)i * 4) = o;
    }
}

// ---------------------------------------------------------------------------
// Kernel 1: fused QKV projection. Double-buffered DMA prefetch, swizzled LDS.
//   z=0: qh (scaled 0.125)  z=1: kh (scaled log2e)  z=2: vt [B,H,HD,L]
// ---------------------------------------------------------------------------
__global__ __launch_bounds__(256) void proj_qkv(
    const bf16* __restrict__ qb, const bf16* __restrict__ kb, const bf16* __restrict__ vb,
    const bf16* __restrict__ wq, const bf16* __restrict__ wk, const bf16* __restrict__ wv,
    const float* __restrict__ biasq, const float* __restrict__ biask, const float* __restrict__ biasv,
    bf16* __restrict__ qh, bf16* __restrict__ kh, bf16* __restrict__ vt)
{
    const int z = blockIdx.z;
    const bf16* X     = (z == 0) ? qb : (z == 1) ? kb : vb;
    const bf16* W     = (z == 0) ? wq : (z == 1) ? wk : wv;
    const float* bias = (z == 0) ? biasq : (z == 1) ? biask : biasv;

    const int m0 = blockIdx.y * 128;
    const int n0 = blockIdx.x * 128;

    __shared__ bf16 As[2][128 * 32];
    __shared__ bf16 Bs[2][128 * 32];

    const int t    = threadIdx.x;
    const int lane = t & 63;
    const int wm   = (t >> 7) & 1;
    const int wn   = (t >> 6) & 1;
    const int quad = lane >> 4;
    const int l16  = lane & 15;

    auto stage = [&](int k0, int buf) {
        #pragma unroll
        for (int p = 0; p < 2; ++p) {
            const int id = p * 256 + t;
            const int r = id >> 2, s = id & 3;
            const int c = (s ^ (r & 3)) * 8;
            g2l16(X + (size_t)(m0 + r) * ND + k0 + c, As[buf] + id * 8);
            g2l16(W + (size_t)(n0 + r) * ND + k0 + c, Bs[buf] + id * 8);
        }
    };

    f32x4 acc[4][4] = {};
    stage(0, 0);

    for (int it = 0; it < 16; ++it) {
        __syncthreads();
        if (it + 1 < 16) stage((it + 1) * 32, (it + 1) & 1);

        const bf16* as = As[it & 1];
        const bf16* bs = Bs[it & 1];
        bf16x8 aF[4], bF[4];
        #pragma unroll
        for (int i = 0; i < 4; ++i) {
            const int ra = wm * 64 + i * 16 + l16;
            const int rb = wn * 64 + i * 16 + l16;
            aF[i] = *(const bf16x8*)(as + ra * 32 + (quad ^ (ra & 3)) * 8);
            bF[i] = *(const bf16x8*)(bs + rb * 32 + (quad ^ (rb & 3)) * 8);
        }
        #pragma unroll
        for (int mt = 0; mt < 4; ++mt)
            #pragma unroll
            for (int nt = 0; nt < 4; ++nt)
                acc[mt][nt] = __builtin_amdgcn_mfma_f32_16x16x32_bf16(
                    aF[mt], bF[nt], acc[mt][nt], 0, 0, 0);
    }

    const float oscale = (z == 0) ? 0.125f : (z == 1) ? 1.4426950408889634f : 1.0f;
    #pragma unroll
    for (int nt = 0; nt < 4; ++nt) {
        const int col = n0 + wn * 64 + nt * 16 + l16;
        const float bb = bias[col];
        const int h = col >> 6, hd = col & 63;
        #pragma unroll
        for (int mt = 0; mt < 4; ++mt) {
            const int row0 = m0 + wm * 64 + mt * 16 + quad * 4;
            const int b = row0 >> 12;
            const int l = row0 & 4095;
            if (z == 2) {
                bf16x4 val;
                #pragma unroll
                for (int r = 0; r < 4; ++r) val[r] = (bf16)(acc[mt][nt][r] + bb);
                *(bf16x4*)(vt + ((size_t)(b * NH + h) * NHD + hd) * NL + l) = val;
            } else {
                bf16* dst = (z == 0) ? qh : kh;
                #pragma unroll
                for (int r = 0; r < 4; ++r)
                    dst[((size_t)(b * NH + h) * NL + (l + r)) * NHD + hd] =
                        (bf16)((acc[mt][nt][r] + bb) * oscale);
            }
        }
    }
}

// ---------------------------------------------------------------------------
// Kernel 2: causal flash attention — uniform split-kv pairs.
// 256 blocks (16 planes x 16 pairs), 512 threads (8 waves).
// Pair (qtA = by, qtB = 31-by): total kv work = 66 iters of BKV=64.
// Waves 0-3 (group 0): tile B, kv [0,33).
// Waves 4-7 (group 1): tile A fully (nA=2qtA+2 <= 32 iters), then tile B
//   kv [33, nB). Exactly 33 iters per group -> all 256 blocks identical.
// Softmax here is a pure sum (static max): O and l are additive over kv;
// group 1's tile-B partials are combined through LDS at the end.
//
// T12: P never touches LDS. Swapped QK^T puts qrow on lane&31 (the PV
// B-operand's n axis); the half-lane axis is fixed with v_cvt_pk_bf16_f32
// (2 f32 -> 1 dword of 2 bf16) + v_permlane32_swap_b32: for chunk c,
//   {word0,word2} = swap(pk(e[b0+0],e[b0+1]), pk(e[b0+4],e[b0+5]))
//   {word1,word3} = swap(pk(e[b0+2],e[b0+3]), pk(e[b0+6],e[b0+7]))
// with b0 = 8*(c&1), e = exp'd sacc[c>>1]  (acc row = (r&3)+8*(r>>2)+4*half).
// This removes 8 ds_write + 4 ds_read per iter, the 4-way-conflicting P
// buffer (36 KB LDS), and ~60 VALU ops/iter.
//
// LDS: 2 streams x 32 KB = 64 KB. Single qf[4]; group 1 reloads tile-B Q
// fragments from global once at jj==nA (replaces the qfA/qfB double hoist).
// ---------------------------------------------------------------------------
__global__ __launch_bounds__(512, 2) void attn(
    const bf16* __restrict__ qh, const bf16* __restrict__ kh,
    const bf16* __restrict__ vt, bf16* __restrict__ ao)
{
    const int bh  = blockIdx.x;          // plane 0..15
    const int b   = bh >> 3, h = bh & 7;
    const int qtA = blockIdx.y;          // 0..15
    const int qtB = 31 - qtA;            // 31..16
    const int nA  = 2 * qtA + 2;         // <= 32

    // smem elems: 2 streams x (2 bufs x (K 4096 | V 4096)) = 64 KB.
    __shared__ bf16 smem[32768];

    const int t    = threadIdx.x;        // 0..511
    const int wave = t >> 6;             // 0..7
    const int g    = wave >> 2;          // group 0/1
    const int w4   = wave & 3;           // wave within group
    const int lane = t & 63;
    const int l32  = lane & 31;
    const int half = lane >> 5;
    const int sb   = g * 16384;          // stream base (elems)
    const int tg   = t & 255;            // thread id within group

    const bf16* Qg = qh + (size_t)bh * NL * NHD;
    const bf16* Kg = kh + (size_t)bh * NL * NHD;
    const bf16* Vg = vt + (size_t)bh * NHD * NL;

    // stage both Q tiles (A at elems 0.., B at 8192..) with all 512 threads
    #pragma unroll
    for (int p = 0; p < 4; ++p) {
        const int id = p * 512 + t;                 // 0..2047 16B chunks
        const int tile = id >> 10, r = (id >> 3) & 127, s = id & 7;
        const int q0 = (tile ? qtB : qtA) * 128;
        g2l16(Qg + (size_t)(q0 + r) * NHD + s * 8, smem + id * 8);
    }
    __syncthreads();

    // hoist this wave's CURRENT tile Q fragments:
    // group 0 -> tile B (offset 8192); group 1 -> tile A (offset 0).
    bf16x8 qf[4];
    {
        const int qoff = (g == 0) ? 8192 : 0;
        #pragma unroll
        for (int c = 0; c < 4; ++c)
            qf[c] = *(const bf16x8*)(smem + qoff + (w4 * 32 + l32) * 64 + c * 16 + half * 8);
    }
    __syncthreads();   // Q reads done before K/V DMA overwrites the region

    // group-local stage: 16 KB (K 8 KB + V 8 KB) by this group's 256 threads
    auto stage_kv = [&](int k0, int buf) {
        #pragma unroll
        for (int p = 0; p < 2; ++p) {
            const int id = p * 256 + tg;            // 0..511
            const int r = id >> 3, s = id & 7;
            g2l16(Kg + (size_t)(k0 + r) * NHD + ((s ^ (r & 7)) * 8),
                  smem + sb + buf * 8192 + id * 8);
            g2l16(Vg + (size_t)r * NL + k0 + ((s ^ (r & 7)) * 8),
                  smem + sb + buf * 8192 + 4096 + id * 8);
        }
    };
    // group 1's schedule: jj<nA -> tile A kv jj ; else tile B kv (jj-nA+33)
    stage_kv(0, 0);   // both groups start at kv tile 0 (of their own tile)

    f32x16 o_acc[2] = {};
    float l_lane = 0.f;

    for (int jj = 0; jj < 33; ++jj) {
        __syncthreads();    // drains DMA for buf[jj&1] of both streams

        if (jj + 1 < 33) {  // prefetch next tile for this group's stream
            const int jn = jj + 1;
            const int kvn = (g == 0) ? jn : (jn < nA ? jn : jn - nA + 33);
            stage_kv(kvn * 64, jn & 1);
        }

        // group 1: tile A finished -> direct epilogue + reset + Q switch
        if (g == 1 && jj == nA) {
            const float lt = l_lane + __shfl_xor(l_lane, 32, 64);
            const float rcp = 1.0f / fmaxf(lt, 1e-20f);
            const int row = qtA * 128 + w4 * 32 + l32;
            #pragma unroll
            for (int mt2 = 0; mt2 < 2; ++mt2)
                #pragma unroll
                for (int rr = 0; rr < 4; ++rr) {
                    const int hd = mt2 * 32 + rr * 8 + half * 4;
                    bf16x4 val;
                    #pragma unroll
                    for (int rb = 0; rb < 4; ++rb)
                        val[rb] = (bf16)(o_acc[mt2][rr * 4 + rb] * rcp);
                    *(bf16x4*)(ao + ((size_t)b * NL + row) * ND + h * NHD + hd) = val;
                }
            o_acc[0] = (f32x16)(0.f); o_acc[1] = (f32x16)(0.f);
            l_lane = 0.f;
            // reload Q fragments for tile B from global (one-time, 4 loads)
            const bf16* Qt = Qg + (size_t)(qtB * 128 + w4 * 32 + l32) * NHD;
            #pragma unroll
            for (int c = 0; c < 4; ++c)
                qf[c] = *(const bf16x8*)(Qt + c * 16 + half * 8);
        }

        const bool useA  = (g == 1) && (jj < nA);
        const int j_glob = (g == 0) ? jj : (useA ? jj : jj - nA + 33);
        const int qt_cur = useA ? qtA : qtB;

        const bf16* ks = smem + sb + (jj & 1) * 8192;
        const bf16* vs = ks + 4096;

        // S^T[kv 64][qrow 32/wave]: 2 kv m-tiles x 4 hd k-chunks
        f32x16 sacc[2] = {};
        #pragma unroll
        for (int c = 0; c < 4; ++c) {
            #pragma unroll
            for (int mt = 0; mt < 2; ++mt) {
                const int row   = mt * 32 + l32;
                const int chunk = 2 * c + half;
                const bf16x8 kf = *(const bf16x8*)(ks + row * 64 + ((chunk ^ (row & 7)) * 8));
                sacc[mt] = __builtin_amdgcn_mfma_f32_32x32x16_bf16(
                    kf, qf[c], sacc[mt], 0, 0, 0);
            }
        }

        // mask + exp2 in place (ln2 folded into K), accumulate l
        const bool diag   = (j_glob >= 2 * qt_cur);
        const int  dq     = j_glob * 64 - qt_cur * 128;   // 0 or 64 when diag
        const int  qrow_l = w4 * 32 + l32;
        #pragma unroll
        for (int mt = 0; mt < 2; ++mt) {
            #pragma unroll
            for (int r = 0; r < 16; ++r) {
                const int kv = mt * 32 + (r & 3) + 8 * (r >> 2) + 4 * half;
                float e;
                if (diag && (dq + kv > qrow_l)) e = 0.f;
                else e = exp2f(sacc[mt][r]);
                l_lane += e;
                sacc[mt][r] = e;
            }
        }

        // O^T[hd 64][qrow 32] += V^T . P^T, with P fragments built in-register
        #pragma unroll
        for (int c = 0; c < 4; ++c) {
            const int mt = c >> 1;
            const int b0 = (c & 1) * 8;
            unsigned w0, w1, w2, w3;
            asm("v_cvt_pk_bf16_f32 %0, %1, %2" : "=v"(w0)
                : "v"(sacc[mt][b0 + 0]), "v"(sacc[mt][b0 + 1]));
            asm("v_cvt_pk_bf16_f32 %0, %1, %2" : "=v"(w1)
                : "v"(sacc[mt][b0 + 2]), "v"(sacc[mt][b0 + 3]));
            asm("v_cvt_pk_bf16_f32 %0, %1, %2" : "=v"(w2)
                : "v"(sacc[mt][b0 + 4]), "v"(sacc[mt][b0 + 5]));
            asm("v_cvt_pk_bf16_f32 %0, %1, %2" : "=v"(w3)
                : "v"(sacc[mt][b0 + 6]), "v"(sacc[mt][b0 + 7]));
            const u32x2 s02 = __builtin_amdgcn_permlane32_swap(w0, w2, false, false);
            const u32x2 s13 = __builtin_amdgcn_permlane32_swap(w1, w3, false, false);
            u32x4 pw_ = { s02.x, s13.x, s02.y, s13.y };
            bf16x8 pf;
            __builtin_memcpy(&pf, &pw_, 16);
            #pragma unroll
            for (int mt2 = 0; mt2 < 2; ++mt2) {
                const int row = mt2 * 32 + l32;
                const int u8  = 2 * c + half;
                const bf16x8 vf = *(const bf16x8*)(vs + row * 64 + ((u8 ^ (row & 7)) * 8));
                o_acc[mt2] = __builtin_amdgcn_mfma_f32_32x32x16_bf16(
                    vf, pf, o_acc[mt2], 0, 0, 0);
            }
        }
    }

    // combine tile-B halves: group 1 -> LDS (f32, stride 36/lane), group 0 adds
    __syncthreads();
    float* comb = (float*)smem;
    if (g == 1) {
        const int base = w4 * (64 * 36) + lane * 36;
        #pragma unroll
        for (int mt2 = 0; mt2 < 2; ++mt2)
            #pragma unroll
            for (int i = 0; i < 16; ++i)
                comb[base + mt2 * 16 + i] = o_acc[mt2][i];
        const float lt = l_lane + __shfl_xor(l_lane, 32, 64);
        if (half == 0) comb[9216 + w4 * 32 + l32] = lt;
    }
    __syncthreads();
    if (g == 0) {
        const int base = w4 * (64 * 36) + lane * 36;
        const float lt = l_lane + __shfl_xor(l_lane, 32, 64)
                       + comb[9216 + w4 * 32 + l32];
        const float rcp = 1.0f / fmaxf(lt, 1e-20f);
        const int row = qtB * 128 + w4 * 32 + l32;
        #pragma unroll
        for (int mt2 = 0; mt2 < 2; ++mt2)
            #pragma unroll
            for (int rr = 0; rr < 4; ++rr) {
                const int hd = mt2 * 32 + rr * 8 + half * 4;
                bf16x4 val;
                #pragma unroll
                for (int rb = 0; rb < 4; ++rb)
                    val[rb] = (bf16)((o_acc[mt2][rr * 4 + rb] +
                                      comb[base + mt2 * 16 + rr * 4 + rb]) * rcp);
                *(bf16x4*)(ao + ((size_t)b * NL + row) * ND + h * NHD + hd) = val;
            }
    }
}

// ---------------------------------------------------------------------------
// Kernel 3: output projection. out(f32) = ao(bf16) @ Wo^T(bf16) + bo(f32).
// ---------------------------------------------------------------------------
__global__ __launch_bounds__(256) void out_proj(
    const bf16* __restrict__ ao, const bf16* __restrict__ wo,
    const float* __restrict__ bo, float* __restrict__ out)
{
    const int m0 = blockIdx.y * 128;
    const int n0 = blockIdx.x * 128;

    __shared__ bf16 As[2][128 * 32];
    __shared__ bf16 Bs[2][128 * 32];

    const int t    = threadIdx.x;
    const int lane = t & 63;
    const int wm   = (t >> 7) & 1;
    const int wn   = (t >> 6) & 1;
    const int quad = lane >> 4;
    const int l16  = lane & 15;

    auto stage = [&](int k0, int buf) {
        #pragma unroll
        for (int p = 0; p < 2; ++p) {
            const int id = p * 256 + t;
            const int r = id >> 2, s = id & 3;
            const int c = (s ^ (r & 3)) * 8;
            g2l16(ao + (size_t)(m0 + r) * ND + k0 + c, As[buf] + id * 8);
            g2l16(wo + (size_t)(n0 + r) * ND + k0 + c, Bs[buf] + id * 8);
        }
    };

    f32x4 acc[4][4] = {};
    stage(0, 0);

    for (int it = 0; it < 16; ++it) {
        __syncthreads();
        if (it + 1 < 16) stage((it + 1) * 32, (it + 1) & 1);

        const bf16* as = As[it & 1];
        const bf16* bs = Bs[it & 1];
        bf16x8 aF[4], bF[4];
        #pragma unroll
        for (int i = 0; i < 4; ++i) {
            const int ra = wm * 64 + i * 16 + l16;
            const int rb = wn * 64 + i * 16 + l16;
            aF[i] = *(const bf16x8*)(as + ra * 32 + (quad ^ (ra & 3)) * 8);
            bF[i] = *(const bf16x8*)(bs + rb * 32 + (quad ^ (rb & 3)) * 8);
        }
        #pragma unroll
        for (int mt = 0; mt < 4; ++mt)
            #pragma unroll
            for (int nt = 0; nt < 4; ++nt)
                acc[mt][nt] = __builtin_amdgcn_mfma_f32_16x16x32_bf16(
                    aF[mt], bF[nt], acc[mt][nt], 0, 0, 0);
    }

    #pragma unroll
    for (int nt = 0; nt < 4; ++nt) {
        const int col = n0 + wn * 64 + nt * 16 + l16;
        const float bb = bo[col];
        #pragma unroll
        for (int mt = 0; mt < 4; ++mt) {
            const int row0 = m0 + wm * 64 + mt * 16 + quad * 4;
            #pragma unroll
            for (int r = 0; r < 4; ++r)
                out[(size_t)(row0 + r) * ND + col] = acc[mt][nt][r] + bb;
        }
    }
}

extern "C" void kernel_launch(void* const* d_in, const int* in_sizes, int n_in,
                              void* d_out, int out_size, void* d_ws, size_t ws_size,
                              hipStream_t stream) {
    (void)in_sizes; (void)n_in; (void)out_size; (void)ws_size;

    const float* q  = (const float*)d_in[0];
    const float* k  = (const float*)d_in[1];
    const float* v  = (const float*)d_in[2];
    // d_in[3] = causal mask: statically known (tril), ignored.
    const float* Wq = (const float*)d_in[4];
    const float* bq = (const float*)d_in[5];
    const float* Wk = (const float*)d_in[6];
    const float* bk = (const float*)d_in[7];
    const float* Wv = (const float*)d_in[8];
    const float* bv = (const float*)d_in[9];
    const float* Wo = (const float*)d_in[10];
    const float* bo = (const float*)d_in[11];

    const size_t XSZ = (size_t)NB * NL * ND;
    const size_t WSZ = (size_t)ND * ND;
    bf16* p = (bf16*)d_ws;
    bf16* qb  = p; p += XSZ;
    bf16* kb  = p; p += XSZ;
    bf16* vb  = p; p += XSZ;
    bf16* wqb = p; p += WSZ;
    bf16* wkb = p; p += WSZ;
    bf16* wvb = p; p += WSZ;
    bf16* wob = p; p += WSZ;
    bf16* qh  = p; p += XSZ;
    bf16* kh  = p; p += XSZ;
    bf16* vt  = p; p += XSZ;
    bf16* ao  = p; p += XSZ;

    cvt_all<<<dim3(512, 1, 7), 256, 0, stream>>>(
        q, k, v, Wq, Wk, Wv, Wo, qb, kb, vb, wqb, wkb, wvb, wob);

    dim3 g1(ND / 128, (NB * NL) / 128, 3);
    proj_qkv<<<g1, 256, 0, stream>>>(qb, kb, vb, wqb, wkb, wvb, bq, bk, bv, qh, kh, vt);

    dim3 g2(16, 16, 1);   // 256 uniform blocks, 512 threads each
    attn<<<g2, 512, 0, stream>>>(qh, kh, vt, ao);

    dim3 g3(ND / 128, (NB * NL) / 128, 1);
    out_proj<<<g3, 256, 0, stream>>>(ao, wob, bo, (float*)d_out);
}

// Round 2
// 239.805 us; speedup vs baseline: 1.0886x; 1.0849x over previous
//
#include <hip/hip_runtime.h>

typedef __bf16 bf16;
typedef __bf16 bf16x4 __attribute__((ext_vector_type(4)));
typedef __bf16 bf16x8 __attribute__((ext_vector_type(8)));
typedef float  f32x4  __attribute__((ext_vector_type(4)));
typedef float  f32x16 __attribute__((ext_vector_type(16)));
typedef unsigned int u32x2 __attribute__((ext_vector_type(2)));
typedef unsigned int u32x4 __attribute__((ext_vector_type(4)));

#define NB   2
#define NL   4096
#define ND   512
#define NH   8
#define NHD  64

// async global->LDS, 16 bytes per lane. LDS dest must be wave-uniform base + lane*16.
static __device__ __forceinline__ void g2l16(const bf16* g, bf16* l) {
    __builtin_amdgcn_global_load_lds(
        (const __attribute__((address_space(1))) unsigned int*)g,
        (__attribute__((address_space(3))) unsigned int*)l, 16, 0, 0);
}

// ---------------------------------------------------------------------------
// Kernel 0: all f32 -> bf16 conversions in one dispatch (memory-bound).
// ---------------------------------------------------------------------------
__global__ __launch_bounds__(256) void cvt_all(
    const float* __restrict__ q, const float* __restrict__ k, const float* __restrict__ v,
    const float* __restrict__ Wq, const float* __restrict__ Wk,
    const float* __restrict__ Wv, const float* __restrict__ Wo,
    bf16* __restrict__ qb, bf16* __restrict__ kb, bf16* __restrict__ vb,
    bf16* __restrict__ wqb, bf16* __restrict__ wkb,
    bf16* __restrict__ wvb, bf16* __restrict__ wob)
{
    const int z = blockIdx.z;
    const float* src; bf16* dst; int n4;
    switch (z) {
        case 0: src = q;  dst = qb;  n4 = NB * NL * ND / 4; break;
        case 1: src = k;  dst = kb;  n4 = NB * NL * ND / 4; break;
        case 2: src = v;  dst = vb;  n4 = NB * NL * ND / 4; break;
        case 3: src = Wq; dst = wqb; n4 = ND * ND / 4; break;
        case 4: src = Wk; dst = wkb; n4 = ND * ND / 4; break;
        case 5: src = Wv; dst = wvb; n4 = ND * ND / 4; break;
        default: src = Wo; dst = wob; n4 = ND * ND / 4; break;
    }
    for (int i = blockIdx.x * 256 + threadIdx.x; i < n4; i += gridDim.x * 256) {
        const f32x4 a = *(const f32x4*)(src + (size_t)i * 4);
        bf16x4 o;
        #pragma unroll
        for (int j = 0; j < 4; ++j) o[j] = (bf16)a[j];
        *(bf16x4*)(dst + (size_t)i * 4) = o;
    }
}

// ---------------------------------------------------------------------------
// Kernel 1: fused QKV projection. Double-buffered DMA prefetch, swizzled LDS.
//   z=0: qh (scaled 0.125)  z=1: kh (scaled log2e)  z=2: vt [B,H,HD,L]
// ---------------------------------------------------------------------------
__global__ __launch_bounds__(256) void proj_qkv(
    const bf16* __restrict__ qb, const bf16* __restrict__ kb, const bf16* __restrict__ vb,
    const bf16* __restrict__ wq, const bf16* __restrict__ wk, const bf16* __restrict__ wv,
    const float* __restrict__ biasq, const float* __restrict__ biask, const float* __restrict__ biasv,
    bf16* __restrict__ qh, bf16* __restrict__ kh, bf16* __restrict__ vt)
{
    const int z = blockIdx.z;
    const bf16* X     = (z == 0) ? qb : (z == 1) ? kb : vb;
    const bf16* W     = (z == 0) ? wq : (z == 1) ? wk : wv;
    const float* bias = (z == 0) ? biasq : (z == 1) ? biask : biasv;

    const int m0 = blockIdx.y * 128;
    const int n0 = blockIdx.x * 128;

    __shared__ bf16 As[2][128 * 32];
    __shared__ bf16 Bs[2][128 * 32];

    const int t    = threadIdx.x;
    const int lane = t & 63;
    const int wm   = (t >> 7) & 1;
    const int wn   = (t >> 6) & 1;
    const int quad = lane >> 4;
    const int l16  = lane & 15;

    auto stage = [&](int k0, int buf) {
        #pragma unroll
        for (int p = 0; p < 2; ++p) {
            const int id = p * 256 + t;
            const int r = id >> 2, s = id & 3;
            const int c = (s ^ (r & 3)) * 8;
            g2l16(X + (size_t)(m0 + r) * ND + k0 + c, As[buf] + id * 8);
            g2l16(W + (size_t)(n0 + r) * ND + k0 + c, Bs[buf] + id * 8);
        }
    };

    f32x4 acc[4][4] = {};
    stage(0, 0);

    for (int it = 0; it < 16; ++it) {
        __syncthreads();
        if (it + 1 < 16) stage((it + 1) * 32, (it + 1) & 1);

        const bf16* as = As[it & 1];
        const bf16* bs = Bs[it & 1];
        bf16x8 aF[4], bF[4];
        #pragma unroll
        for (int i = 0; i < 4; ++i) {
            const int ra = wm * 64 + i * 16 + l16;
            const int rb = wn * 64 + i * 16 + l16;
            aF[i] = *(const bf16x8*)(as + ra * 32 + (quad ^ (ra & 3)) * 8);
            bF[i] = *(const bf16x8*)(bs + rb * 32 + (quad ^ (rb & 3)) * 8);
        }
        #pragma unroll
        for (int mt = 0; mt < 4; ++mt)
            #pragma unroll
            for (int nt = 0; nt < 4; ++nt)
                acc[mt][nt] = __builtin_amdgcn_mfma_f32_16x16x32_bf16(
                    aF[mt], bF[nt], acc[mt][nt], 0, 0, 0);
    }

    const float oscale = (z == 0) ? 0.125f : (z == 1) ? 1.4426950408889634f : 1.0f;
    #pragma unroll
    for (int nt = 0; nt < 4; ++nt) {
        const int col = n0 + wn * 64 + nt * 16 + l16;
        const float bb = bias[col];
        const int h = col >> 6, hd = col & 63;
        #pragma unroll
        for (int mt = 0; mt < 4; ++mt) {
            const int row0 = m0 + wm * 64 + mt * 16 + quad * 4;
            const int b = row0 >> 12;
            const int l = row0 & 4095;
            if (z == 2) {
                bf16x4 val;
                #pragma unroll
                for (int r = 0; r < 4; ++r) val[r] = (bf16)(acc[mt][nt][r] + bb);
                *(bf16x4*)(vt + ((size_t)(b * NH + h) * NHD + hd) * NL + l) = val;
            } else {
                bf16* dst = (z == 0) ? qh : kh;
                #pragma unroll
                for (int r = 0; r < 4; ++r)
                    dst[((size_t)(b * NH + h) * NL + (l + r)) * NHD + hd] =
                        (bf16)((acc[mt][nt][r] + bb) * oscale);
            }
        }
    }
}

// ---------------------------------------------------------------------------
// Kernel 2: causal flash attention — uniform split-kv pairs, BKV=128.
// 256 blocks (16 planes x 16 pairs), 512 threads (8 waves).
// Pair (qtA = by, qtB = 31-qtA): total kv work = 33 tiles of BKV=128.
// Waves 0-3 (group 0): tile B, kv tiles [15-qtA, 32-qtA)  (17 tiles).
// Waves 4-7 (group 1): tile A fully (nA' = qtA+1 <= 16 tiles), then tile B
//   kv tiles [0, 15-qtA)  (16 tiles total; idle compute slot at jj=16).
// Loop runs 17 iters -> per-iteration barrier/drain fixed cost is paid 17x
// instead of 33x (round-1 evidence: removing per-iter WORK changed nothing,
// so the per-iter FIXED cost dominates; halve its count instead).
// Each staged 128-kv tile is consumed as two 64-kv sub-tiles (ksub loop)
// reusing the round-1 compute body unchanged.
//
// Softmax is a pure sum (static max): O and l additive over kv; group 1's
// tile-B partials combined through LDS at the end.
// T12 P-in-register path (cvt_pk_bf16 + permlane32_swap) unchanged.
// exp2f -> __builtin_amdgcn_exp2f (raw v_exp_f32; inputs bounded, masked
// lanes forced to 0, so no OCML edge-case fixup needed).
//
// LDS: 2 streams x 2 bufs x (K 16KB + V 16KB) = 128 KB (static; 100 KB
// static worked in round 0). V stored as [2 ksub][64 hd][64 kv] halves so
// the round-1 swizzle carries over verbatim.
// ---------------------------------------------------------------------------
__global__ __launch_bounds__(512, 2) void attn(
    const bf16* __restrict__ qh, const bf16* __restrict__ kh,
    const bf16* __restrict__ vt, bf16* __restrict__ ao)
{
    const int bh  = blockIdx.x;          // plane 0..15
    const int b   = bh >> 3, h = bh & 7;
    const int qtA = blockIdx.y;          // 0..15
    const int qtB = 31 - qtA;            // 31..16
    const int nAp = qtA + 1;             // tile-A 128-tiles, <= 16

    // 65536 bf16 elems = 128 KB: stream g at g*32768; buf at +buf*16384;
    // K [128][64] at +0 (8192 elems), V [2][64][64] at +8192.
    __shared__ bf16 smem[65536];

    const int t    = threadIdx.x;        // 0..511
    const int wave = t >> 6;             // 0..7
    const int g    = wave >> 2;          // group 0/1
    const int w4   = wave & 3;           // wave within group
    const int lane = t & 63;
    const int l32  = lane & 31;
    const int half = lane >> 5;
    const int sb   = g * 32768;          // stream base (elems)
    const int tg   = t & 255;            // thread id within group

    const bf16* Qg = qh + (size_t)bh * NL * NHD;
    const bf16* Kg = kh + (size_t)bh * NL * NHD;
    const bf16* Vg = vt + (size_t)bh * NHD * NL;

    // stage both Q tiles (A at elems 0.., B at 8192..) with all 512 threads
    #pragma unroll
    for (int p = 0; p < 4; ++p) {
        const int id = p * 512 + t;                 // 0..2047 16B chunks
        const int tile = id >> 10, r = (id >> 3) & 127, s = id & 7;
        const int q0 = (tile ? qtB : qtA) * 128;
        g2l16(Qg + (size_t)(q0 + r) * NHD + s * 8, smem + id * 8);
    }
    __syncthreads();

    // hoist this wave's CURRENT tile Q fragments:
    // group 0 -> tile B (offset 8192); group 1 -> tile A (offset 0).
    bf16x8 qf[4];
    {
        const int qoff = (g == 0) ? 8192 : 0;
        #pragma unroll
        for (int c = 0; c < 4; ++c)
            qf[c] = *(const bf16x8*)(smem + qoff + (w4 * 32 + l32) * 64 + c * 16 + half * 8);
    }
    __syncthreads();   // Q reads done before K/V DMA overwrites the region

    // group-local stage: 64 KB tile (K 16KB rows 0..127 + V 16KB as 2 halves)
    auto stage_kv = [&](int k0, int buf) {
        bf16* kd = smem + sb + buf * 16384;
        bf16* vd = kd + 8192;
        #pragma unroll
        for (int p = 0; p < 4; ++p) {
            const int id = p * 256 + tg;            // 0..1023
            const int r = id >> 3, s = id & 7;      // K: row 0..127, chunk 0..7
            g2l16(Kg + (size_t)(k0 + r) * NHD + ((s ^ (r & 7)) * 8), kd + id * 8);
            const int ks2 = id >> 9, idh = id & 511;
            const int r2 = idh >> 3, s2 = idh & 7;  // V: hd row 0..63, chunk 0..7
            g2l16(Vg + (size_t)r2 * NL + k0 + ks2 * 64 + ((s2 ^ (r2 & 7)) * 8),
                  vd + id * 8);
        }
    };

    // first 128-tile per group: group0 -> 15-qtA, group1 -> 0 (tile A)
    stage_kv(((g == 0) ? (15 - qtA) : 0) * 128, 0);

    f32x16 o_acc[2] = {};
    float l_lane = 0.f;

    for (int jj = 0; jj < 17; ++jj) {
        __syncthreads();    // drains DMA for buf[jj&1] of both streams

        if (jj + 1 < 17) {  // prefetch next 128-tile for this group's stream
            const int jn = jj + 1;
            if (g == 0)          stage_kv((15 - qtA + jn) * 128, jn & 1);
            else if (jn < 16)    stage_kv(((jn < nAp) ? jn : jn - nAp) * 128, jn & 1);
        }

        // group 1: tile A finished -> direct epilogue + reset + Q switch
        if (g == 1 && jj == nAp) {
            const float lt = l_lane + __shfl_xor(l_lane, 32, 64);
            const float rcp = 1.0f / fmaxf(lt, 1e-20f);
            const int row = qtA * 128 + w4 * 32 + l32;
            #pragma unroll
            for (int mt2 = 0; mt2 < 2; ++mt2)
                #pragma unroll
                for (int rr = 0; rr < 4; ++rr) {
                    const int hd = mt2 * 32 + rr * 8 + half * 4;
                    bf16x4 val;
                    #pragma unroll
                    for (int rb = 0; rb < 4; ++rb)
                        val[rb] = (bf16)(o_acc[mt2][rr * 4 + rb] * rcp);
                    *(bf16x4*)(ao + ((size_t)b * NL + row) * ND + h * NHD + hd) = val;
                }
            o_acc[0] = (f32x16)(0.f); o_acc[1] = (f32x16)(0.f);
            l_lane = 0.f;
            // reload Q fragments for tile B from global (one-time, 4 loads)
            const bf16* Qt = Qg + (size_t)(qtB * 128 + w4 * 32 + l32) * NHD;
            #pragma unroll
            for (int c = 0; c < 4; ++c)
                qf[c] = *(const bf16x8*)(Qt + c * 16 + half * 8);
        }

        const bool act = (g == 0) || (jj < 16);
        if (act) {
            const bool onA   = (g == 1) && (jj < nAp);
            const int tile   = (g == 0) ? (15 - qtA + jj) : (onA ? jj : jj - nAp);
            const int qt_cur = onA ? qtA : qtB;
            const bf16* kb_ = smem + sb + (jj & 1) * 16384;
            const bf16* vb_ = kb_ + 8192;
            const int qrow_l = w4 * 32 + l32;

            #pragma unroll
            for (int ksub = 0; ksub < 2; ++ksub) {
                const bf16* ks_ = kb_ + ksub * 4096;   // K rows ksub*64..+63
                const bf16* vs_ = vb_ + ksub * 4096;   // V half ksub
                const int j64 = tile * 2 + ksub;       // 64-kv sub-tile index

                // S^T[kv 64][qrow 32/wave]: 2 kv m-tiles x 4 hd k-chunks
                f32x16 sacc[2] = {};
                #pragma unroll
                for (int c = 0; c < 4; ++c) {
                    #pragma unroll
                    for (int mt = 0; mt < 2; ++mt) {
                        const int row   = mt * 32 + l32;
                        const int chunk = 2 * c + half;
                        const bf16x8 kf = *(const bf16x8*)(ks_ + row * 64 + ((chunk ^ (row & 7)) * 8));
                        sacc[mt] = __builtin_amdgcn_mfma_f32_32x32x16_bf16(
                            kf, qf[c], sacc[mt], 0, 0, 0);
                    }
                }

                // mask + exp2 in place (ln2 folded into K), accumulate l
                const bool diag = (j64 >= 2 * qt_cur);
                const int  dq   = j64 * 64 - qt_cur * 128;
                #pragma unroll
                for (int mt = 0; mt < 2; ++mt) {
                    #pragma unroll
                    for (int r = 0; r < 16; ++r) {
                        const int kv = mt * 32 + (r & 3) + 8 * (r >> 2) + 4 * half;
                        float e;
                        if (diag && (dq + kv > qrow_l)) e = 0.f;
                        else e = __builtin_amdgcn_exp2f(sacc[mt][r]);
                        l_lane += e;
                        sacc[mt][r] = e;
                    }
                }

                // O^T[hd 64][qrow 32] += V^T . P^T, P fragments in-register
                #pragma unroll
                for (int c = 0; c < 4; ++c) {
                    const int mt = c >> 1;
                    const int b0 = (c & 1) * 8;
                    unsigned w0, w1, w2, w3;
                    asm("v_cvt_pk_bf16_f32 %0, %1, %2" : "=v"(w0)
                        : "v"(sacc[mt][b0 + 0]), "v"(sacc[mt][b0 + 1]));
                    asm("v_cvt_pk_bf16_f32 %0, %1, %2" : "=v"(w1)
                        : "v"(sacc[mt][b0 + 2]), "v"(sacc[mt][b0 + 3]));
                    asm("v_cvt_pk_bf16_f32 %0, %1, %2" : "=v"(w2)
                        : "v"(sacc[mt][b0 + 4]), "v"(sacc[mt][b0 + 5]));
                    asm("v_cvt_pk_bf16_f32 %0, %1, %2" : "=v"(w3)
                        : "v"(sacc[mt][b0 + 6]), "v"(sacc[mt][b0 + 7]));
                    const u32x2 s02 = __builtin_amdgcn_permlane32_swap(w0, w2, false, false);
                    const u32x2 s13 = __builtin_amdgcn_permlane32_swap(w1, w3, false, false);
                    u32x4 pw_ = { s02.x, s13.x, s02.y, s13.y };
                    bf16x8 pf;
                    __builtin_memcpy(&pf, &pw_, 16);
                    #pragma unroll
                    for (int mt2 = 0; mt2 < 2; ++mt2) {
                        const int row = mt2 * 32 + l32;
                        const int u8  = 2 * c + half;
                        const bf16x8 vf = *(const bf16x8*)(vs_ + row * 64 + ((u8 ^ (row & 7)) * 8));
                        o_acc[mt2] = __builtin_amdgcn_mfma_f32_32x32x16_bf16(
                            vf, pf, o_acc[mt2], 0, 0, 0);
                    }
                }
            }
        }
    }

    // combine tile-B halves: group 1 -> LDS (f32, stride 36/lane), group 0 adds
    __syncthreads();
    float* comb = (float*)smem;
    if (g == 1) {
        const int base = w4 * (64 * 36) + lane * 36;
        #pragma unroll
        for (int mt2 = 0; mt2 < 2; ++mt2)
            #pragma unroll
            for (int i = 0; i < 16; ++i)
                comb[base + mt2 * 16 + i] = o_acc[mt2][i];
        const float lt = l_lane + __shfl_xor(l_lane, 32, 64);
        if (half == 0) comb[9216 + w4 * 32 + l32] = lt;
    }
    __syncthreads();
    if (g == 0) {
        const int base = w4 * (64 * 36) + lane * 36;
        const float lt = l_lane + __shfl_xor(l_lane, 32, 64)
                       + comb[9216 + w4 * 32 + l32];
        const float rcp = 1.0f / fmaxf(lt, 1e-20f);
        const int row = qtB * 128 + w4 * 32 + l32;
        #pragma unroll
        for (int mt2 = 0; mt2 < 2; ++mt2)
            #pragma unroll
            for (int rr = 0; rr < 4; ++rr) {
                const int hd = mt2 * 32 + rr * 8 + half * 4;
                bf16x4 val;
                #pragma unroll
                for (int rb = 0; rb < 4; ++rb)
                    val[rb] = (bf16)((o_acc[mt2][rr * 4 + rb] +
                                      comb[base + mt2 * 16 + rr * 4 + rb]) * rcp);
                *(bf16x4*)(ao + ((size_t)b * NL + row) * ND + h * NHD + hd) = val;
            }
    }
}

// ---------------------------------------------------------------------------
// Kernel 3: output projection. out(f32) = ao(bf16) @ Wo^T(bf16) + bo(f32).
// ---------------------------------------------------------------------------
__global__ __launch_bounds__(256) void out_proj(
    const bf16* __restrict__ ao, const bf16* __restrict__ wo,
    const float* __restrict__ bo, float* __restrict__ out)
{
    const int m0 = blockIdx.y * 128;
    const int n0 = blockIdx.x * 128;

    __shared__ bf16 As[2][128 * 32];
    __shared__ bf16 Bs[2][128 * 32];

    const int t    = threadIdx.x;
    const int lane = t & 63;
    const int wm   = (t >> 7) & 1;
    const int wn   = (t >> 6) & 1;
    const int quad = lane >> 4;
    const int l16  = lane & 15;

    auto stage = [&](int k0, int buf) {
        #pragma unroll
        for (int p = 0; p < 2; ++p) {
            const int id = p * 256 + t;
            const int r = id >> 2, s = id & 3;
            const int c = (s ^ (r & 3)) * 8;
            g2l16(ao + (size_t)(m0 + r) * ND + k0 + c, As[buf] + id * 8);
            g2l16(wo + (size_t)(n0 + r) * ND + k0 + c, Bs[buf] + id * 8);
        }
    };

    f32x4 acc[4][4] = {};
    stage(0, 0);

    for (int it = 0; it < 16; ++it) {
        __syncthreads();
        if (it + 1 < 16) stage((it + 1) * 32, (it + 1) & 1);

        const bf16* as = As[it & 1];
        const bf16* bs = Bs[it & 1];
        bf16x8 aF[4], bF[4];
        #pragma unroll
        for (int i = 0; i < 4; ++i) {
            const int ra = wm * 64 + i * 16 + l16;
            const int rb = wn * 64 + i * 16 + l16;
            aF[i] = *(const bf16x8*)(as + ra * 32 + (quad ^ (ra & 3)) * 8);
            bF[i] = *(const bf16x8*)(bs + rb * 32 + (quad ^ (rb & 3)) * 8);
        }
        #pragma unroll
        for (int mt = 0; mt < 4; ++mt)
            #pragma unroll
            for (int nt = 0; nt < 4; ++nt)
                acc[mt][nt] = __builtin_amdgcn_mfma_f32_16x16x32_bf16(
                    aF[mt], bF[nt], acc[mt][nt], 0, 0, 0);
    }

    #pragma unroll
    for (int nt = 0; nt < 4; ++nt) {
        const int col = n0 + wn * 64 + nt * 16 + l16;
        const float bb = bo[col];
        #pragma unroll
        for (int mt = 0; mt < 4; ++mt) {
            const int row0 = m0 + wm * 64 + mt * 16 + quad * 4;
            #pragma unroll
            for (int r = 0; r < 4; ++r)
                out[(size_t)(row0 + r) * ND + col] = acc[mt][nt][r] + bb;
        }
    }
}

extern "C" void kernel_launch(void* const* d_in, const int* in_sizes, int n_in,
                              void* d_out, int out_size, void* d_ws, size_t ws_size,
                              hipStream_t stream) {
    (void)in_sizes; (void)n_in; (void)out_size; (void)ws_size;

    const float* q  = (const float*)d_in[0];
    const float* k  = (const float*)d_in[1];
    const float* v  = (const float*)d_in[2];
    // d_in[3] = causal mask: statically known (tril), ignored.
    const float* Wq = (const float*)d_in[4];
    const float* bq = (const float*)d_in[5];
    const float* Wk = (const float*)d_in[6];
    const float* bk = (const float*)d_in[7];
    const float* Wv = (const float*)d_in[8];
    const float* bv = (const float*)d_in[9];
    const float* Wo = (const float*)d_in[10];
    const float* bo = (const float*)d_in[11];

    const size_t XSZ = (size_t)NB * NL * ND;
    const size_t WSZ = (size_t)ND * ND;
    bf16* p = (bf16*)d_ws;
    bf16* qb  = p; p += XSZ;
    bf16* kb  = p; p += XSZ;
    bf16* vb  = p; p += XSZ;
    bf16* wqb = p; p += WSZ;
    bf16* wkb = p; p += WSZ;
    bf16* wvb = p; p += WSZ;
    bf16* wob = p; p += WSZ;
    bf16* qh  = p; p += XSZ;
    bf16* kh  = p; p += XSZ;
    bf16* vt  = p; p += XSZ;
    bf16* ao  = p; p += XSZ;

    cvt_all<<<dim3(512, 1, 7), 256, 0, stream>>>(
        q, k, v, Wq, Wk, Wv, Wo, qb, kb, vb, wqb, wkb, wvb, wob);

    dim3 g1(ND / 128, (NB * NL) / 128, 3);
    proj_qkv<<<g1, 256, 0, stream>>>(qb, kb, vb, wqb, wkb, wvb, bq, bk, bv, qh, kh, vt);

    dim3 g2(16, 16, 1);   // 256 uniform blocks, 512 threads each
    attn<<<g2, 512, 0, stream>>>(qh, kh, vt, ao);

    dim3 g3(ND / 128, (NB * NL) / 128, 1);
    out_proj<<<g3, 256, 0, stream>>>(ao, wob, bo, (float*)d_out);
}